// Round 4
// baseline (681.713 us; speedup 1.0000x reference)
//
#include <hip/hip_runtime.h>

#define NU 60000
#define NI 40000
#define NN 100000
#define NE 1000000
#define NE2 2000000
#define DC 64

#define KPB 25
#define NB 4000   // NN / KPB exactly

// fixed softmax shifts (scores are dots of unit vectors, scaled by 1/8)
#define M_CONV1 0.375f
#define M_ROUTE 0.125f

typedef unsigned short u16;

__device__ __forceinline__ float grp16_sum(float v) {
    v += __shfl_xor(v, 1, 64);
    v += __shfl_xor(v, 2, 64);
    v += __shfl_xor(v, 4, 64);
    v += __shfl_xor(v, 8, 64);
    return v;
}
__device__ __forceinline__ float xgrp_sum(float v) {  // across the 4 groups
    v += __shfl_xor(v, 16, 64);
    v += __shfl_xor(v, 32, 64);
    return v;
}
__device__ __forceinline__ float4 xgrp_sum4(float4 v) {
    v.x = xgrp_sum(v.x); v.y = xgrp_sum(v.y); v.z = xgrp_sum(v.z); v.w = xgrp_sum(v.w);
    return v;
}
__device__ __forceinline__ float dot4(float4 a, float4 b) {
    return a.x * b.x + a.y * b.y + a.z * b.z + a.w * b.w;
}
__device__ __forceinline__ u16 f2b(float f) {
    union { float f; unsigned u; } a; a.f = f;
    unsigned r = a.u + 0x7FFFu + ((a.u >> 16) & 1u);
    return (u16)(r >> 16);
}
__device__ __forceinline__ float b2f(u16 b) {
    union { unsigned u; float f; } a; a.u = ((unsigned)b) << 16;
    return a.f;
}
__device__ __forceinline__ float4 b2f4(ushort4 h) {
    float4 f; f.x = b2f(h.x); f.y = b2f(h.y); f.z = b2f(h.z); f.w = b2f(h.w);
    return f;
}

// ---------------- node init ----------------
__global__ __launch_bounds__(256) void k_init(const float* __restrict__ f1,
                                              const float* __restrict__ f2,
                                              const float* __restrict__ f3,
                                              const float* __restrict__ pref,
                                              float* __restrict__ x0,
                                              u16* __restrict__ x016,
                                              float* __restrict__ w) {
    int node = (blockIdx.x * blockDim.x + threadIdx.x) >> 6;
    int lane = threadIdx.x & 63;
    if (node >= NN) return;
    float outv;
    if (node < NU) {
        float v = pref[node * DC + lane];
        float s = v * v;
#pragma unroll
        for (int o = 32; o > 0; o >>= 1) s += __shfl_xor(s, o, 64);
        outv = v / fmaxf(sqrtf(s), 1e-12f);
    } else {
        int it = node - NU;
        float a = f1[it * DC + lane];
        float b = f2[it * DC + lane];
        float c = f3[it * DC + lane];
        float sa = a * a, sb = b * b, sc = c * c;
#pragma unroll
        for (int o = 32; o > 0; o >>= 1) {
            sa += __shfl_xor(sa, o, 64);
            sb += __shfl_xor(sb, o, 64);
            sc += __shfl_xor(sc, o, 64);
        }
        outv = a / fmaxf(sqrtf(sa), 1e-12f);
        w[it * DC + lane] = outv + b / fmaxf(sqrtf(sb), 1e-12f) + c / fmaxf(sqrtf(sc), 1e-12f);
    }
    x0[node * DC + lane] = outv;
    x016[node * DC + lane] = f2b(outv);
}

// ---------------- CSR build ----------------
__global__ __launch_bounds__(256) void k_count(const int* __restrict__ ei,
                                               int* __restrict__ cnt) {
    int e = blockIdx.x * blockDim.x + threadIdx.x;
    if (e >= NE2) return;
    int dst = (e < NE) ? ei[NE + e] : ei[e - NE];
    atomicAdd(&cnt[dst], 1);
}

__device__ __forceinline__ int block_exscan1024(int v) {
    __shared__ int wsum[16];
    int tid = threadIdx.x, lane = tid & 63;
    int wv = tid >> 6;
    int inc = v;
#pragma unroll
    for (int o = 1; o < 64; o <<= 1) {
        int t = __shfl_up(inc, o, 64);
        if (lane >= o) inc += t;
    }
    if (lane == 63) wsum[wv] = inc;
    __syncthreads();
    if (tid < 16) {
        int b = wsum[tid];
        int binc = b;
#pragma unroll
        for (int o = 1; o < 16; o <<= 1) {
            int t = __shfl_up(binc, o, 16);
            if (tid >= o) binc += t;
        }
        wsum[tid] = binc - b;
    }
    __syncthreads();
    return wsum[wv] + inc - v;
}

__global__ __launch_bounds__(1024) void k_scan1(const int* __restrict__ cnt,
                                                int* __restrict__ off,
                                                int* __restrict__ bsum) {
    int i = blockIdx.x * 1024 + threadIdx.x;
    int v = (i < NN) ? cnt[i] : 0;
    int ex = block_exscan1024(v);
    if (i < NN) off[i] = ex;
    if (threadIdx.x == 1023) bsum[blockIdx.x] = ex + v;
}

__global__ __launch_bounds__(1024) void k_scan2(int* __restrict__ bsum, int nb) {
    int v = (threadIdx.x < nb) ? bsum[threadIdx.x] : 0;
    int ex = block_exscan1024(v);
    if (threadIdx.x < nb) bsum[threadIdx.x] = ex;
}

__global__ __launch_bounds__(1024) void k_scan3(int* __restrict__ off,
                                                const int* __restrict__ bsum,
                                                int* __restrict__ bcur) {
    int i = blockIdx.x * 1024 + threadIdx.x;
    if (i < NN) {
        int o = off[i] + bsum[blockIdx.x];
        off[i] = o;
        if (i % KPB == 0) bcur[i / KPB] = o;
    }
    if (i == 0) off[NN] = NE2;
}

// phase A: bin edges by dst/KPB; bucket regions == final CSR ranges
__global__ __launch_bounds__(256) void k_bin(const int* __restrict__ ei,
                                             int* __restrict__ bcur,
                                             int2* __restrict__ binned) {
    int e = blockIdx.x * blockDim.x + threadIdx.x;
    if (e >= NE2) return;
    int src = ei[e];
    int dst = (e < NE) ? ei[NE + e] : ei[e - NE];
    int b = dst / KPB;
    int drel = dst - b * KPB;
    int pos = atomicAdd(&bcur[b], 1);
    int2 v; v.x = src; v.y = (e << 5) | drel;
    binned[pos] = v;
}

// phase B: per-bucket placement via LDS cursors (writes land contiguous)
__global__ __launch_bounds__(128) void k_fill2(const int2* __restrict__ binned,
                                               const int* __restrict__ off,
                                               int* __restrict__ esrcF,
                                               int* __restrict__ eidF) {
    int b = blockIdx.x;
    __shared__ int cur[KPB];
    int t = threadIdx.x;
    if (t < KPB) cur[t] = off[b * KPB + t];
    __syncthreads();
    int s = off[b * KPB], e = off[b * KPB + KPB];
    for (int p = s + t; p < e; p += 128) {
        int2 v = binned[p];
        int drel = v.y & 31;
        int pos = atomicAdd(&cur[drel], 1);
        esrcF[pos] = v.x;
        eidF[pos] = v.y >> 5;
    }
}

// ---------------- conv1: multimodal GAT with threshold + re-attention ----------------
// 16 edges per wave iteration, 4 chains, shfl-distributed indices
__global__ __launch_bounds__(256) void k_conv1(const float* __restrict__ x0,
                                               const float* __restrict__ w,
                                               const u16* __restrict__ x16,
                                               const int* __restrict__ off,
                                               const int* __restrict__ eid,
                                               const int* __restrict__ esrc,
                                               float* __restrict__ sE,
                                               float* __restrict__ x1,
                                               u16* __restrict__ x116,
                                               float* __restrict__ aout) {
    int node = (blockIdx.x * blockDim.x + threadIdx.x) >> 6;
    int lane = threadIdx.x & 63;
    if (node >= NN) return;
    int grp = lane >> 4, gl = lane & 15;
    int beg = off[node], end = off[node + 1];
    bool user = (node < NU);

    float4 xi4 = *((const float4*)(x0 + (size_t)node * DC) + gl);
    float4 ai4 = user ? xi4 : *((const float4*)(w + (size_t)(node - NU) * DC) + gl);
    const float* gbase = user ? w : x0;
    int goff = user ? NU : 0;

    // pass A: f32 scores -> e = exp(lrelu(s) - M); den; stage e
    float den = 0.f;
    for (int p0 = beg; p0 < end; p0 += 16) {
        int pl = p0 + lane;
        int eidx = (lane < 16 && pl < end) ? (esrc[pl] - goff) : 0;
        int s0[4]; float4 g[4];
#pragma unroll
        for (int c = 0; c < 4; ++c) {
            s0[c] = __shfl(eidx, 4 * c + grp, 64);
            g[c] = *((const float4*)(gbase + (size_t)s0[c] * DC) + gl);
        }
#pragma unroll
        for (int c = 0; c < 4; ++c) {
            int p = p0 + 4 * c + grp;
            bool act = p < end;
            float d = grp16_sum(dot4(ai4, g[c])) * 0.125f;
            d = (d > 0.f) ? d : 0.2f * d;
            float e = act ? __expf(d - M_CONV1) : 0.f;
            den += e;
            if (act && gl == 0) sE[p] = e;
        }
    }
    den = xgrp_sum(den);
    float invden = 1.f / (den + 1e-16f);
    asm volatile("s_waitcnt vmcnt(0)" ::: "memory");

    // pass B: threshold, den2, aggregate bf16 x[src]
    float den2 = 0.f;
    float4 xh = {0.f, 0.f, 0.f, 0.f};
    for (int p0 = beg; p0 < end; p0 += 16) {
        int pl = p0 + lane;
        bool ldok = (lane < 16 && pl < end);
        int eidx = ldok ? esrc[pl] : 0;
        float sv = ldok ? sE[pl] : 0.f;
        int s0[4]; ushort4 h[4];
#pragma unroll
        for (int c = 0; c < 4; ++c) {
            s0[c] = __shfl(eidx, 4 * c + grp, 64);
            h[c] = *((const ushort4*)(x16 + (size_t)s0[c] * DC) + gl);
        }
#pragma unroll
        for (int c = 0; c < 4; ++c) {
            float e = __shfl(sv, 4 * c + grp, 64);
            float a = e * invden;
            float t = (a > 0.02f) ? a : 0.f;
            den2 += t;
            float4 f = b2f4(h[c]);
            xh.x += t * f.x; xh.y += t * f.y; xh.z += t * f.z; xh.w += t * f.w;
        }
    }
    den2 = xgrp_sum(den2);
    xh = xgrp_sum4(xh);
    float invden2 = 1.f / (den2 + 1e-16f);

    // pass C: write re-normalized alpha at original edge ids
    for (int p = beg + lane; p < end; p += 64) {
        float a = sE[p] * invden;
        float t = (a > 0.02f) ? a : 0.f;
        aout[eid[p]] = t * invden2;
    }

    // node update: x = l2norm(x + x_hat)
    float4 v;
    v.x = xi4.x + xh.x * invden2;
    v.y = xi4.y + xh.y * invden2;
    v.z = xi4.z + xh.z * invden2;
    v.w = xi4.w + xh.w * invden2;
    float nn = grp16_sum(dot4(v, v));
    float inv_n = 1.f / fmaxf(sqrtf(nn), 1e-12f);
    if (grp == 0) {
        float4 o = {v.x * inv_n, v.y * inv_n, v.z * inv_n, v.w * inv_n};
        *((float4*)(x1 + (size_t)node * DC) + gl) = o;
        ushort4 h = {f2b(o.x), f2b(o.y), f2b(o.z), f2b(o.w)};
        *((ushort4*)(x116 + (size_t)node * DC) + gl) = h;
    }
}

// ---------------- routing: plain dot-product GAT, single pass, bf16 gathers ----------------
__global__ __launch_bounds__(256) void k_route(const float* __restrict__ xin,
                                               const u16* __restrict__ g16,
                                               const int* __restrict__ off,
                                               const int* __restrict__ esrc,
                                               float* __restrict__ xout,
                                               u16* __restrict__ out16) {
    int node = (blockIdx.x * blockDim.x + threadIdx.x) >> 6;
    int lane = threadIdx.x & 63;
    if (node >= NN) return;
    int grp = lane >> 4, gl = lane & 15;
    int beg = off[node], end = off[node + 1];

    float4 xi4 = *((const float4*)(xin + (size_t)node * DC) + gl);

    float den = 0.f;
    float4 xh = {0.f, 0.f, 0.f, 0.f};
    for (int p0 = beg; p0 < end; p0 += 16) {
        int pl = p0 + lane;
        int eidx = (lane < 16 && pl < end) ? esrc[pl] : 0;
        int s0[4]; ushort4 h[4];
#pragma unroll
        for (int c = 0; c < 4; ++c) {
            s0[c] = __shfl(eidx, 4 * c + grp, 64);
            h[c] = *((const ushort4*)(g16 + (size_t)s0[c] * DC) + gl);
        }
#pragma unroll
        for (int c = 0; c < 4; ++c) {
            bool act = (p0 + 4 * c + grp) < end;
            float4 f = b2f4(h[c]);
            float d = grp16_sum(dot4(xi4, f)) * 0.125f;
            d = (d > 0.f) ? d : 0.2f * d;
            float e = act ? __expf(d - M_ROUTE) : 0.f;
            den += e;
            xh.x += e * f.x; xh.y += e * f.y; xh.z += e * f.z; xh.w += e * f.w;
        }
    }
    den = xgrp_sum(den);
    xh = xgrp_sum4(xh);
    float inv = 1.f / (den + 1e-16f);

    float4 v;
    v.x = xi4.x + xh.x * inv;
    v.y = xi4.y + xh.y * inv;
    v.z = xi4.z + xh.z * inv;
    v.w = xi4.w + xh.w * inv;
    float nn = grp16_sum(dot4(v, v));
    float inv_n = 1.f / fmaxf(sqrtf(nn), 1e-12f);
    if (grp == 0) {
        float4 o = {v.x * inv_n, v.y * inv_n, v.z * inv_n, v.w * inv_n};
        *((float4*)(xout + (size_t)node * DC) + gl) = o;
        ushort4 h = {f2b(o.x), f2b(o.y), f2b(o.z), f2b(o.w)};
        *((ushort4*)(out16 + (size_t)node * DC) + gl) = h;
    }
}

extern "C" void kernel_launch(void* const* d_in, const int* in_sizes, int n_in,
                              void* d_out, int out_size, void* d_ws, size_t ws_size,
                              hipStream_t stream) {
    const float* f1   = (const float*)d_in[0];
    const float* f2   = (const float*)d_in[1];
    const float* f3   = (const float*)d_in[2];
    const float* pref = (const float*)d_in[3];
    const int*   ei   = (const int*)d_in[4];

    float* out  = (float*)d_out;
    float* x0   = out;                       // ping buffer A (final x lands here)
    float* aout = out + (size_t)NN * DC;

    float* xb   = (float*)d_ws;              // ping buffer B (f32)
    float* w    = xb + (size_t)NN * DC;
    int2*  binned = (int2*)(w + (size_t)NI * DC);   // 16MB; sE aliases (disjoint lifetime)
    float* sE   = (float*)binned;
    u16*  xa16  = (u16*)(binned + NE2);
    u16*  xb16  = xa16 + (size_t)NN * DC;
    int* cnt    = (int*)(xb16 + (size_t)NN * DC);
    int* off    = cnt + NN;
    int* bsum   = off + NN + 1;
    int* bcur   = bsum + 1024;
    int* eid    = bcur + NB;
    int* esrc   = eid + NE2;

    hipMemsetAsync(cnt, 0, NN * sizeof(int), stream);

    int nb = (NN + 1023) / 1024;
    k_init<<<(NN * 64) / 256, 256, 0, stream>>>(f1, f2, f3, pref, x0, xa16, w);
    k_count<<<(NE2 + 255) / 256, 256, 0, stream>>>(ei, cnt);
    k_scan1<<<nb, 1024, 0, stream>>>(cnt, off, bsum);
    k_scan2<<<1, 1024, 0, stream>>>(bsum, nb);
    k_scan3<<<nb, 1024, 0, stream>>>(off, bsum, bcur);
    k_bin<<<(NE2 + 255) / 256, 256, 0, stream>>>(ei, bcur, binned);
    k_fill2<<<NB, 128, 0, stream>>>(binned, off, esrc, eid);

    // conv1: x0 -> xb (+xb16), alpha -> aout  (scores f32, aggregation bf16)
    k_conv1<<<(NN * 64) / 256, 256, 0, stream>>>(x0, w, xa16, off, eid, esrc, sE, xb, xb16, aout);
    // routing x3: xb -> x0 -> xb -> x0 (final in d_out)
    k_route<<<(NN * 64) / 256, 256, 0, stream>>>(xb, xb16, off, esrc, x0, xa16);
    k_route<<<(NN * 64) / 256, 256, 0, stream>>>(x0, xa16, off, esrc, xb, xb16);
    k_route<<<(NN * 64) / 256, 256, 0, stream>>>(xb, xb16, off, esrc, x0, xa16);
}